// Round 1
// baseline (273.261 us; speedup 1.0000x reference)
//
#include <hip/hip_runtime.h>
#include <math.h>

constexpr int N_ROWS = 1024;
constexpr int DDIM   = 512;
constexpr int C_CLS  = 100000;
constexpr int BM = 128, BN = 128, BK = 32;
constexpr int NT = (C_CLS + BN - 1) / BN;   // 782 class tiles
constexpr int KTILES = DDIM / BK;           // 16
constexpr float MARG = 0.4f;

typedef __attribute__((ext_vector_type(8))) short bf16x8;   // 8 bf16 (4 VGPRs)
typedef __attribute__((ext_vector_type(4))) float f32x4;

__device__ __forceinline__ unsigned int f2bf(float x) {
    union { float f; unsigned int u; } v; v.f = x;
    return (v.u + 0x7FFFu + ((v.u >> 16) & 1u)) >> 16;   // RNE to bf16 bits
}

__device__ __forceinline__ float wave_sum(float s) {
    #pragma unroll
    for (int m = 1; m < 64; m <<= 1) s += __shfl_xor(s, m, 64);
    return s;
}

// ---- kernel 1: per-row norm of embs -> g[i], normalized bf16 ehat ----
__global__ __launch_bounds__(256) void prep_embs(const float* __restrict__ embs,
                                                 float* __restrict__ g,
                                                 unsigned short* __restrict__ ehat) {
    const int row  = blockIdx.x * 4 + (threadIdx.x >> 6);
    const int lane = threadIdx.x & 63;
    const float4* src = (const float4*)(embs + (size_t)row * DDIM + lane * 8);
    const float4 a = src[0], b = src[1];
    float ss = a.x*a.x + a.y*a.y + a.z*a.z + a.w*a.w
             + b.x*b.x + b.y*b.y + b.z*b.z + b.w*b.w;
    ss = wave_sum(ss);
    const float norm = sqrtf(ss);
    const float rn = 1.f / norm;
    if (lane == 0) {
        float gg = (norm - 20.f) / sqrtf(10000.f + 1e-3f) * 0.333f;
        gg = fminf(fmaxf(gg, -1.f), 1.f);
        g[row] = gg;
    }
    uint4 pk;
    pk.x = f2bf(a.x*rn) | (f2bf(a.y*rn) << 16);
    pk.y = f2bf(a.z*rn) | (f2bf(a.w*rn) << 16);
    pk.z = f2bf(b.x*rn) | (f2bf(b.y*rn) << 16);
    pk.w = f2bf(b.z*rn) | (f2bf(b.w*rn) << 16);
    *(uint4*)(ehat + (size_t)row * DDIM + lane * 8) = pk;
}

// ---- kernel 2: 1/||weight[c]|| ----
__global__ __launch_bounds__(256) void prep_wnorm(const float* __restrict__ w,
                                                  float* __restrict__ rnormw) {
    const int row  = blockIdx.x * 4 + (threadIdx.x >> 6);
    const int lane = threadIdx.x & 63;
    const float4* src = (const float4*)(w + (size_t)row * DDIM + lane * 8);
    const float4 a = src[0], b = src[1];
    float ss = a.x*a.x + a.y*a.y + a.z*a.z + a.w*a.w
             + b.x*b.x + b.y*b.y + b.z*b.z + b.w*b.w;
    ss = wave_sum(ss);
    if (lane == 0) rnormw[row] = 1.f / sqrtf(ss);
}

// ---- kernel 3: fused GEMM + per-tile exp-sum partials ----
__global__ __launch_bounds__(256, 2) void gemm_fused(
        const unsigned short* __restrict__ ehat,   // [1024][512] bf16
        const float* __restrict__ weight,          // [100000][512]
        const float* __restrict__ rnormw,          // [100000]
        const int* __restrict__ labels,            // [1024]
        float* __restrict__ psum,                  // [1024][NT]
        float* __restrict__ dlab)                  // [1024] raw clipped label logit
{
    __shared__ __align__(16) unsigned short As[BM * BK];  // 8 KB [row][k]
    __shared__ __align__(16) unsigned short Bs[BN * BK];  // 8 KB [col][k]
    __shared__ float redbuf[2][BM];                       // 1 KB

    const int bid    = blockIdx.x;
    const int tile_c = bid >> 3;           // adjacent bids share a class tile (L2/L3 locality)
    const int tile_r = bid & 7;
    const int row0   = tile_r * BM;
    const int col0   = tile_c * BN;

    const int tid  = threadIdx.x;
    const int lane = tid & 63;
    const int wv   = tid >> 6;
    const int wr   = wv >> 1;   // 0..1 : row half
    const int wc   = wv & 1;    // 0..1 : col half

    f32x4 acc[4][4];
    #pragma unroll
    for (int m = 0; m < 4; ++m)
        #pragma unroll
        for (int n = 0; n < 4; ++n) acc[m][n] = f32x4{0.f, 0.f, 0.f, 0.f};

    // B staging map: tid -> (col-in-tile = p*32 + tid/8, float4 index tid%8); hoist rnorm
    const int kq    = tid & 7;
    const int brow0 = tid >> 3;
    int   cidx[4];
    float rnv[4];
    #pragma unroll
    for (int p = 0; p < 4; ++p) {
        int c = col0 + p * 32 + brow0;
        c = c < C_CLS ? c : C_CLS - 1;    // tail tile: clamp (masked in epilogue)
        cidx[p] = c;
        rnv[p]  = rnormw[c];
    }

    for (int kt = 0; kt < KTILES; ++kt) {
        const int kbase = kt * BK;
        // A: 128x32 bf16, reg-staged 16B/thread x2
        #pragma unroll
        for (int call = 0; call < 2; ++call) {
            const int chunk = call * 256 + tid;           // 0..511
            const uint4 d = *(const uint4*)(ehat + (size_t)(row0 + (chunk >> 2)) * DDIM
                                            + kbase + (chunk & 3) * 8);
            *(uint4*)(As + chunk * 8) = d;
        }
        // B: 128x32 fp32 -> scale -> bf16
        #pragma unroll
        for (int p = 0; p < 4; ++p) {
            const float4 wd = *(const float4*)(weight + (size_t)cidx[p] * DDIM + kbase + kq * 4);
            const float r = rnv[p];
            const unsigned int lo = f2bf(wd.x * r) | (f2bf(wd.y * r) << 16);
            const unsigned int hi = f2bf(wd.z * r) | (f2bf(wd.w * r) << 16);
            *(uint2*)(Bs + (p * 32 + brow0) * BK + kq * 4) = make_uint2(lo, hi);
        }
        __syncthreads();

        bf16x8 af[4], bf[4];
        const int lr  = lane & 15;
        const int lko = (lane >> 4) * 8;
        #pragma unroll
        for (int m = 0; m < 4; ++m)
            af[m] = *(const bf16x8*)(As + (wr * 64 + m * 16 + lr) * BK + lko);
        #pragma unroll
        for (int n = 0; n < 4; ++n)
            bf[n] = *(const bf16x8*)(Bs + (wc * 64 + n * 16 + lr) * BK + lko);
        #pragma unroll
        for (int m = 0; m < 4; ++m)
            #pragma unroll
            for (int n = 0; n < 4; ++n)
                acc[m][n] = __builtin_amdgcn_mfma_f32_16x16x32_bf16(af[m], bf[n], acc[m][n], 0, 0, 0);
        __syncthreads();
    }

    // epilogue: clip, capture label logit, sum exp(S*v - 64) per row over this tile
    #pragma unroll
    for (int m = 0; m < 4; ++m) {
        #pragma unroll
        for (int j = 0; j < 4; ++j) {
            const int lrow  = wr * 64 + m * 16 + ((lane >> 4) << 2) + j;
            const int r_abs = row0 + lrow;
            const int lab   = labels[r_abs];
            float s = 0.f;
            #pragma unroll
            for (int n = 0; n < 4; ++n) {
                const int c_abs = col0 + wc * 64 + n * 16 + (lane & 15);
                float v = acc[m][n][j];
                v = fminf(fmaxf(v, -0.999f), 0.999f);
                if (c_abs == lab) dlab[r_abs] = v;
                if (c_abs < C_CLS) s += __expf(64.f * v - 64.f);
            }
            #pragma unroll
            for (int msk = 1; msk < 16; msk <<= 1) s += __shfl_xor(s, msk, 64);
            if ((lane & 15) == 0) redbuf[wc][lrow] = s;
        }
    }
    __syncthreads();
    for (int t = tid; t < BM; t += 256)
        psum[(size_t)(row0 + t) * NT + tile_c] = redbuf[0][t] + redbuf[1][t];
}

// ---- kernel 4: per-row combine + margin correction at label ----
__global__ __launch_bounds__(256) void reduce_rows(const float* __restrict__ psum,
                                                   const float* __restrict__ dlab,
                                                   const float* __restrict__ g,
                                                   float* __restrict__ losses) {
    const int row  = blockIdx.x * 4 + (threadIdx.x >> 6);
    const int lane = threadIdx.x & 63;
    const float* p = psum + (size_t)row * NT;
    float s = 0.f;
    for (int t = lane; t < NT; t += 64) s += p[t];
    s = wave_sum(s);
    if (lane == 0) {
        const float v  = dlab[row];            // already clipped to [-0.999, 0.999]
        const float gg = g[row];
        float th = acosf(v) - MARG * gg;
        th = fminf(fmaxf(th, 0.f), 3.14159265358979323846f);
        const float vm = cosf(th) - (1.f + MARG) * gg;
        // swap unmargined label term for margined one
        s = s - __expf(64.f * v - 64.f) + __expf(64.f * vm - 64.f);
        losses[row] = 64.f + logf(s) - 64.f * vm;   // lse - S*m_label
    }
}

// ---- kernel 5: mean over rows ----
__global__ __launch_bounds__(256) void final_mean(const float* __restrict__ losses,
                                                  float* __restrict__ out) {
    const int tid = threadIdx.x;
    float s = 0.f;
    #pragma unroll
    for (int i = 0; i < 4; ++i) s += losses[tid + i * 256];
    s = wave_sum(s);
    __shared__ float red[4];
    if ((tid & 63) == 0) red[tid >> 6] = s;
    __syncthreads();
    if (tid == 0) out[0] = (red[0] + red[1] + red[2] + red[3]) * (1.f / 1024.f);
}

extern "C" void kernel_launch(void* const* d_in, const int* in_sizes, int n_in,
                              void* d_out, int out_size, void* d_ws, size_t ws_size,
                              hipStream_t stream) {
    const float* embs   = (const float*)d_in[0];
    const float* weight = (const float*)d_in[1];
    const int*   labels = (const int*)d_in[2];
    float* out = (float*)d_out;
    float* ws  = (float*)d_ws;

    // ws layout (floats): total ~4.67 MB
    float* rnormw = ws + 0;                               // 100000 (pad to 100352)
    float* gbuf   = ws + 100352;                          // 1024
    float* dlab   = ws + 101376;                          // 1024
    float* losses = ws + 102400;                          // 1024
    unsigned short* ehat = (unsigned short*)(ws + 103424);// 1024*512 bf16 = 262144 floats
    float* psum   = ws + 103424 + 262144;                 // 1024*NT

    prep_embs <<<N_ROWS / 4, 256, 0, stream>>>(embs, gbuf, ehat);
    prep_wnorm<<<C_CLS / 4, 256, 0, stream>>>(weight, rnormw);
    gemm_fused<<<NT * 8, 256, 0, stream>>>(ehat, weight, rnormw, labels, psum, dlab);
    reduce_rows<<<N_ROWS / 4, 256, 0, stream>>>(psum, dlab, gbuf, losses);
    final_mean<<<1, 256, 0, stream>>>(losses, out);
}

// Round 2
// 218.624 us; speedup vs baseline: 1.2499x; 1.2499x over previous
//
#include <hip/hip_runtime.h>
#include <math.h>

constexpr int N_ROWS = 1024;
constexpr int DDIM   = 512;
constexpr int C_CLS  = 100000;
constexpr int BM = 128, BN = 128, BK = 32;
constexpr int NT = (C_CLS + BN - 1) / BN;   // 782 class tiles
constexpr int KTILES = DDIM / BK;           // 16
constexpr float MARG = 0.4f;
constexpr int WPAD = 100352;                // padded class count (782*128=100096 <= 100352)

typedef __attribute__((ext_vector_type(8))) short bf16x8;   // 8 bf16 (4 VGPRs)
typedef __attribute__((ext_vector_type(4))) float f32x4;
typedef __attribute__((address_space(1))) const void gvoid_t;
typedef __attribute__((address_space(3))) void lvoid_t;

__device__ __forceinline__ unsigned int f2bf(float x) {
    union { float f; unsigned int u; } v; v.f = x;
    return (v.u + 0x7FFFu + ((v.u >> 16) & 1u)) >> 16;   // RNE to bf16 bits
}

__device__ __forceinline__ float wave_sum(float s) {
    #pragma unroll
    for (int m = 1; m < 64; m <<= 1) s += __shfl_xor(s, m, 64);
    return s;
}

// ---- per-row norm of embs -> g[i], normalized bf16 ehat ----
__global__ __launch_bounds__(256) void prep_embs(const float* __restrict__ embs,
                                                 float* __restrict__ g,
                                                 unsigned short* __restrict__ ehat) {
    const int row  = blockIdx.x * 4 + (threadIdx.x >> 6);
    const int lane = threadIdx.x & 63;
    const float4* src = (const float4*)(embs + (size_t)row * DDIM + lane * 8);
    const float4 a = src[0], b = src[1];
    float ss = a.x*a.x + a.y*a.y + a.z*a.z + a.w*a.w
             + b.x*b.x + b.y*b.y + b.z*b.z + b.w*b.w;
    ss = wave_sum(ss);
    const float norm = sqrtf(ss);
    const float rn = 1.f / norm;
    if (lane == 0) {
        float gg = (norm - 20.f) / sqrtf(10000.f + 1e-3f) * 0.333f;
        gg = fminf(fmaxf(gg, -1.f), 1.f);
        g[row] = gg;
    }
    uint4 pk;
    pk.x = f2bf(a.x*rn) | (f2bf(a.y*rn) << 16);
    pk.y = f2bf(a.z*rn) | (f2bf(a.w*rn) << 16);
    pk.z = f2bf(b.x*rn) | (f2bf(b.y*rn) << 16);
    pk.w = f2bf(b.z*rn) | (f2bf(b.w*rn) << 16);
    *(uint4*)(ehat + (size_t)row * DDIM + lane * 8) = pk;
}

// ---- normalized bf16 weight: what[c] = weight[c] / ||weight[c]|| ----
__global__ __launch_bounds__(256) void prep_what(const float* __restrict__ w,
                                                 unsigned short* __restrict__ what) {
    const int row  = blockIdx.x * 4 + (threadIdx.x >> 6);
    const int lane = threadIdx.x & 63;
    const float4* src = (const float4*)(w + (size_t)row * DDIM + lane * 8);
    const float4 a = src[0], b = src[1];
    float ss = a.x*a.x + a.y*a.y + a.z*a.z + a.w*a.w
             + b.x*b.x + b.y*b.y + b.z*b.z + b.w*b.w;
    ss = wave_sum(ss);
    const float rn = rsqrtf(ss);
    uint4 pk;
    pk.x = f2bf(a.x*rn) | (f2bf(a.y*rn) << 16);
    pk.y = f2bf(a.z*rn) | (f2bf(a.w*rn) << 16);
    pk.z = f2bf(b.x*rn) | (f2bf(b.y*rn) << 16);
    pk.w = f2bf(b.z*rn) | (f2bf(b.w*rn) << 16);
    *(uint4*)(what + (size_t)row * DDIM + lane * 8) = pk;
}

// ---- fallback-path helper: 1/||weight[c]|| ----
__global__ __launch_bounds__(256) void prep_wnorm(const float* __restrict__ w,
                                                  float* __restrict__ rnormw) {
    const int row  = blockIdx.x * 4 + (threadIdx.x >> 6);
    const int lane = threadIdx.x & 63;
    const float4* src = (const float4*)(w + (size_t)row * DDIM + lane * 8);
    const float4 a = src[0], b = src[1];
    float ss = a.x*a.x + a.y*a.y + a.z*a.z + a.w*a.w
             + b.x*b.x + b.y*b.y + b.z*b.z + b.w*b.w;
    ss = wave_sum(ss);
    if (lane == 0) rnormw[row] = 1.f / sqrtf(ss);
}

// ---- fused GEMM + per-tile exp-sum partials ----
// PRE=1: B is pre-normalized bf16 (what), both operands staged via global_load_lds.
// PRE=0: round-1 path (fp32 weight, reg-staged scale+convert).
template<int PRE>
__global__ __launch_bounds__(256, 2) void gemm_fused(
        const unsigned short* __restrict__ ehat,   // [1024][512] bf16
        const unsigned short* __restrict__ whatb,  // [WPAD][512] bf16 (PRE=1)
        const float* __restrict__ weight,          // [100000][512] (PRE=0)
        const float* __restrict__ rnormw,          // [100000]      (PRE=0)
        const int* __restrict__ labels,            // [1024]
        float* __restrict__ psum,                  // [1024][NT]
        float* __restrict__ dlab)                  // [1024] raw clipped label logit
{
    __shared__ __align__(16) unsigned short As[BM * BK];  // 8 KB [row][k]
    __shared__ __align__(16) unsigned short Bs[BN * BK];  // 8 KB [col][k]
    __shared__ float redbuf[2][BM];                       // 1 KB

    const int bid    = blockIdx.x;
    const int tile_c = bid >> 3;           // adjacent bids share a class tile (L2/L3 locality)
    const int tile_r = bid & 7;
    const int row0   = tile_r * BM;
    const int col0   = tile_c * BN;

    const int tid  = threadIdx.x;
    const int lane = tid & 63;
    const int wv   = tid >> 6;
    const int wr   = wv >> 1;   // 0..1 : row half
    const int wc   = wv & 1;    // 0..1 : col half

    f32x4 acc[4][4];
    #pragma unroll
    for (int m = 0; m < 4; ++m)
        #pragma unroll
        for (int n = 0; n < 4; ++n) acc[m][n] = f32x4{0.f, 0.f, 0.f, 0.f};

    // PRE=0 staging map
    const int kq    = tid & 7;
    const int brow0 = tid >> 3;
    int   cidx[4];
    float rnv[4];
    if constexpr (!PRE) {
        #pragma unroll
        for (int p = 0; p < 4; ++p) {
            int c = col0 + p * 32 + brow0;
            c = c < C_CLS ? c : C_CLS - 1;
            cidx[p] = c;
            rnv[p]  = rnormw[c];
        }
    }
    // PRE=1 staging map: lane -> (row srow, 16B k-chunk skc); wave w iter i -> 16 rows
    const int srow = lane >> 2;
    const int skc  = (lane & 3) * 8;

    for (int kt = 0; kt < KTILES; ++kt) {
        const int kbase = kt * BK;
        if constexpr (PRE) {
            #pragma unroll
            for (int i = 0; i < 2; ++i) {
                const int ra = (i * 4 + wv) * 16;        // wave-uniform row base
                const unsigned short* ga = ehat + (size_t)(row0 + ra + srow) * DDIM + kbase + skc;
                __builtin_amdgcn_global_load_lds((gvoid_t*)ga, (lvoid_t*)(As + ra * BK), 16, 0, 0);
                const unsigned short* gb = whatb + (size_t)(col0 + ra + srow) * DDIM + kbase + skc;
                __builtin_amdgcn_global_load_lds((gvoid_t*)gb, (lvoid_t*)(Bs + ra * BK), 16, 0, 0);
            }
        } else {
            #pragma unroll
            for (int call = 0; call < 2; ++call) {
                const int chunk = call * 256 + tid;           // 0..511
                const uint4 d = *(const uint4*)(ehat + (size_t)(row0 + (chunk >> 2)) * DDIM
                                                + kbase + (chunk & 3) * 8);
                *(uint4*)(As + chunk * 8) = d;
            }
            #pragma unroll
            for (int p = 0; p < 4; ++p) {
                const float4 wd = *(const float4*)(weight + (size_t)cidx[p] * DDIM + kbase + kq * 4);
                const float r = rnv[p];
                const unsigned int lo = f2bf(wd.x * r) | (f2bf(wd.y * r) << 16);
                const unsigned int hi = f2bf(wd.z * r) | (f2bf(wd.w * r) << 16);
                *(uint2*)(Bs + (p * 32 + brow0) * BK + kq * 4) = make_uint2(lo, hi);
            }
        }
        __syncthreads();

        bf16x8 af[4], bf[4];
        const int lr  = lane & 15;
        const int lko = (lane >> 4) * 8;
        #pragma unroll
        for (int m = 0; m < 4; ++m)
            af[m] = *(const bf16x8*)(As + (wr * 64 + m * 16 + lr) * BK + lko);
        #pragma unroll
        for (int n = 0; n < 4; ++n)
            bf[n] = *(const bf16x8*)(Bs + (wc * 64 + n * 16 + lr) * BK + lko);
        #pragma unroll
        for (int m = 0; m < 4; ++m)
            #pragma unroll
            for (int n = 0; n < 4; ++n)
                acc[m][n] = __builtin_amdgcn_mfma_f32_16x16x32_bf16(af[m], bf[n], acc[m][n], 0, 0, 0);
        __syncthreads();
    }

    // epilogue: clip, capture label logit, sum exp(S*v - 64) per row over this tile
    #pragma unroll
    for (int m = 0; m < 4; ++m) {
        #pragma unroll
        for (int j = 0; j < 4; ++j) {
            const int lrow  = wr * 64 + m * 16 + ((lane >> 4) << 2) + j;
            const int r_abs = row0 + lrow;
            const int lab   = labels[r_abs];
            float s = 0.f;
            #pragma unroll
            for (int n = 0; n < 4; ++n) {
                const int c_abs = col0 + wc * 64 + n * 16 + (lane & 15);
                float v = acc[m][n][j];
                v = fminf(fmaxf(v, -0.999f), 0.999f);
                if (c_abs == lab) dlab[r_abs] = v;
                if (c_abs < C_CLS) s += __expf(64.f * v - 64.f);
            }
            #pragma unroll
            for (int msk = 1; msk < 16; msk <<= 1) s += __shfl_xor(s, msk, 64);
            if ((lane & 15) == 0) redbuf[wc][lrow] = s;
        }
    }
    __syncthreads();
    for (int t = tid; t < BM; t += 256)
        psum[(size_t)(row0 + t) * NT + tile_c] = redbuf[0][t] + redbuf[1][t];
}

// ---- per-row combine + margin correction at label ----
__global__ __launch_bounds__(256) void reduce_rows(const float* __restrict__ psum,
                                                   const float* __restrict__ dlab,
                                                   const float* __restrict__ g,
                                                   float* __restrict__ losses) {
    const int row  = blockIdx.x * 4 + (threadIdx.x >> 6);
    const int lane = threadIdx.x & 63;
    const float* p = psum + (size_t)row * NT;
    float s = 0.f;
    for (int t = lane; t < NT; t += 64) s += p[t];
    s = wave_sum(s);
    if (lane == 0) {
        const float v  = dlab[row];            // already clipped to [-0.999, 0.999]
        const float gg = g[row];
        float th = acosf(v) - MARG * gg;
        th = fminf(fmaxf(th, 0.f), 3.14159265358979323846f);
        const float vm = cosf(th) - (1.f + MARG) * gg;
        s = s - __expf(64.f * v - 64.f) + __expf(64.f * vm - 64.f);
        losses[row] = 64.f + logf(s) - 64.f * vm;   // lse - S*m_label
    }
}

// ---- mean over rows ----
__global__ __launch_bounds__(256) void final_mean(const float* __restrict__ losses,
                                                  float* __restrict__ out) {
    const int tid = threadIdx.x;
    float s = 0.f;
    #pragma unroll
    for (int i = 0; i < 4; ++i) s += losses[tid + i * 256];
    s = wave_sum(s);
    __shared__ float red[4];
    if ((tid & 63) == 0) red[tid >> 6] = s;
    __syncthreads();
    if (tid == 0) out[0] = (red[0] + red[1] + red[2] + red[3]) * (1.f / 1024.f);
}

extern "C" void kernel_launch(void* const* d_in, const int* in_sizes, int n_in,
                              void* d_out, int out_size, void* d_ws, size_t ws_size,
                              hipStream_t stream) {
    const float* embs   = (const float*)d_in[0];
    const float* weight = (const float*)d_in[1];
    const int*   labels = (const int*)d_in[2];
    float* out = (float*)d_out;
    float* ws  = (float*)d_ws;

    // prenorm-path layout (floats): what | ehat | psum | g | dlab | losses
    const size_t WHAT_F = (size_t)WPAD * DDIM / 2;          // 25,690,112
    const size_t EHAT_F = (size_t)N_ROWS * DDIM / 2;        // 262,144
    const size_t PSUM_F = (size_t)N_ROWS * NT;              // 800,768
    const size_t NEED_F = WHAT_F + EHAT_F + PSUM_F + 3 * 1024;

    if (ws_size >= NEED_F * sizeof(float)) {
        unsigned short* what = (unsigned short*)ws;
        unsigned short* ehat = (unsigned short*)(ws + WHAT_F);
        float* psum   = ws + WHAT_F + EHAT_F;
        float* gbuf   = psum + PSUM_F;
        float* dlab   = gbuf + 1024;
        float* losses = dlab + 1024;

        prep_embs<<<N_ROWS / 4, 256, 0, stream>>>(embs, gbuf, ehat);
        prep_what<<<C_CLS / 4, 256, 0, stream>>>(weight, what);
        gemm_fused<1><<<NT * 8, 256, 0, stream>>>(ehat, what, weight, nullptr, labels, psum, dlab);
        reduce_rows<<<N_ROWS / 4, 256, 0, stream>>>(psum, dlab, gbuf, losses);
        final_mean<<<1, 256, 0, stream>>>(losses, out);
    } else {
        // round-1 fallback layout
        float* rnormw = ws + 0;                               // 100000 (pad to 100352)
        float* gbuf   = ws + 100352;                          // 1024
        float* dlab   = ws + 101376;                          // 1024
        float* losses = ws + 102400;                          // 1024
        unsigned short* ehat = (unsigned short*)(ws + 103424);// 1024*512 bf16
        float* psum   = ws + 103424 + 262144;                 // 1024*NT

        prep_embs <<<N_ROWS / 4, 256, 0, stream>>>(embs, gbuf, ehat);
        prep_wnorm<<<C_CLS / 4, 256, 0, stream>>>(weight, rnormw);
        gemm_fused<0><<<NT * 8, 256, 0, stream>>>(ehat, nullptr, weight, rnormw, labels, psum, dlab);
        reduce_rows<<<N_ROWS / 4, 256, 0, stream>>>(psum, dlab, gbuf, losses);
        final_mean<<<1, 256, 0, stream>>>(losses, out);
    }
}